// Round 1
// baseline (272.452 us; speedup 1.0000x reference)
//
#include <hip/hip_runtime.h>
#include <hip/hip_bf16.h>
#include <math.h>
#include <stdint.h>

#define B_  4
#define C_  256
#define N_  4096
#define HD_ 128

typedef __attribute__((ext_vector_type(8))) short bf16x8;
typedef __attribute__((ext_vector_type(4))) float f32x4;
typedef __attribute__((ext_vector_type(4))) int   i32x4;

#define WF_SHORTS   ((size_t)4*8*8*2*512)    // W fragment tiles, 4 jobs
#define PROJ_SHORTS ((size_t)4*256*4*2*512)  // per projection job
#define VT_SHORTS   ((size_t)4*128*16*512)   // per direction

static __device__ __forceinline__ short f2bf(float x){
  union { float f; unsigned u; } v; v.f = x;
  unsigned r = v.u + 0x7fffu + ((v.u >> 16) & 1u);
  return (short)(r >> 16);
}
static __device__ __forceinline__ float bf2f(short h){
  union { unsigned u; float f; } v; v.u = ((unsigned)(unsigned short)h) << 16;
  return v.f;
}

// ---------------- Phase 0: W -> A-operand hi/lo fragment tiles ----------------
// frag elem j of lane l: W[d = dt*16 + (l&15)][c = ck*32 + 4*(l>>4) + (j&3) + 16*(j>>2)]
__global__ void wfrag_kernel(const float* __restrict__ w0, const float* __restrict__ w1,
                             const float* __restrict__ w2, const float* __restrict__ w3,
                             short* __restrict__ wf)
{
  int job = blockIdx.x, dt = blockIdx.y, ck = blockIdx.z;
  const float* W = job==0 ? w0 : (job==1 ? w1 : (job==2 ? w2 : w3));
  int l = threadIdx.x, g = l>>4, ln = l&15;
  bf16x8 hi, lo;
#pragma unroll
  for (int j=0;j<8;j++){
    int d = dt*16 + ln;
    int c = ck*32 + 4*g + (j&3) + 16*(j>>2);
    float x = W[d*C_ + c];
    short h = f2bf(x);
    hi[j] = h;
    lo[j] = f2bf(x - bf2f(h));
  }
  size_t base = (((size_t)(job*8+dt)*8 + ck)*2)*512 + (size_t)l*8;
  *reinterpret_cast<bf16x8*>(wf + base)       = hi;
  *reinterpret_cast<bf16x8*>(wf + base + 512) = lo;
}

// ---------------- Phase 1: projections (swapped MFMA, 3-pass hi/lo) ----------------
// grid (16 nblk, 4 b, 4 job), block 256 (4 waves), each wave n=64
__global__ __launch_bounds__(256,2) void proj_kernel(
    const float* __restrict__ Xi, const float* __restrict__ Xt,
    const short* __restrict__ wf,
    const float* __restrict__ bnq_g, const float* __restrict__ bnq_b,
    const float* __restrict__ bnq_m, const float* __restrict__ bnq_v,
    const float* __restrict__ bnk_g, const float* __restrict__ bnk_b,
    const float* __restrict__ bnk_m, const float* __restrict__ bnk_v,
    const float* __restrict__ btk, const float* __restrict__ btq,
    short* __restrict__ proj)
{
  const int job = blockIdx.z, b = blockIdx.y;
  const int tid = threadIdx.x, wid = tid>>6, l = tid&63, g = l>>4, ln = l&15;
  const float* X = (job==0 || job==3) ? Xi : Xt;
  const int n0 = blockIdx.x*256 + wid*64;

  const f32x4 fzero = {0.f,0.f,0.f,0.f};
  f32x4 acc[4][8];
#pragma unroll
  for (int nt=0;nt<4;nt++)
#pragma unroll
    for (int dt=0;dt<8;dt++) acc[nt][dt] = fzero;

#pragma unroll 1
  for (int ck=0; ck<8; ck++){
    bf16x8 Bh[4], Bl[4];
#pragma unroll
    for (int nt=0;nt<4;nt++){
#pragma unroll
      for (int j=0;j<8;j++){
        int c = ck*32 + 4*g + (j&3) + 16*(j>>2);
        int n = n0 + nt*16 + ln;
        float x = X[((size_t)b*C_ + c)*N_ + n];
        short h = f2bf(x);
        Bh[nt][j] = h;
        Bl[nt][j] = f2bf(x - bf2f(h));
      }
    }
#pragma unroll
    for (int dt=0;dt<8;dt++){
      const short* af = wf + (((size_t)(job*8+dt)*8 + ck)*2)*512 + (size_t)l*8;
      bf16x8 Ah = *reinterpret_cast<const bf16x8*>(af);
      bf16x8 Al = *reinterpret_cast<const bf16x8*>(af + 512);
#pragma unroll
      for (int nt=0;nt<4;nt++){
        acc[nt][dt] = __builtin_amdgcn_mfma_f32_16x16x32_bf16(Ah, Bh[nt], acc[nt][dt], 0,0,0);
        acc[nt][dt] = __builtin_amdgcn_mfma_f32_16x16x32_bf16(Ah, Bl[nt], acc[nt][dt], 0,0,0);
        acc[nt][dt] = __builtin_amdgcn_mfma_f32_16x16x32_bf16(Al, Bh[nt], acc[nt][dt], 0,0,0);
      }
    }
  }

  // epilogue: affine (BN fold / bias) then hi/lo split into fragment tiles
#pragma unroll
  for (int nt=0;nt<4;nt++){
    int tglob = (n0>>4) + nt;
#pragma unroll
    for (int kc=0;kc<4;kc++){
      bf16x8 hi, lo;
#pragma unroll
      for (int j=0;j<8;j++){
        int dt = 2*kc + (j>>2), r = j&3;
        int d = dt*16 + 4*g + r;
        float y = acc[nt][dt][r];
        float s, t;
        if (job==0){ s = bnq_g[d]*rsqrtf(bnq_v[d]+1e-5f); t = bnq_b[d]-bnq_m[d]*s; }
        else if (job==3){ s = bnk_g[d]*rsqrtf(bnk_v[d]+1e-5f); t = bnk_b[d]-bnk_m[d]*s; }
        else if (job==1){ s = 1.f; t = btk[d]; }
        else            { s = 1.f; t = btq[d]; }
        y = y*s + t;
        short h = f2bf(y);
        hi[j] = h;
        lo[j] = f2bf(y - bf2f(h));
      }
      short* dst = proj + (size_t)job*PROJ_SHORTS
                 + ((((size_t)b*256 + tglob)*4 + kc)*2)*512 + (size_t)l*8;
      *reinterpret_cast<bf16x8*>(dst)       = hi;
      *reinterpret_cast<bf16x8*>(dst + 512) = lo;
    }
  }
}

// ---------------- Phase 1b: V -> V^T A-operand bf16 fragment tiles ----------------
// grid (128 kt, 4 b, 2 dir), block 512
__global__ __launch_bounds__(512,1) void vtile_kernel(
    const float* __restrict__ Xi, const float* __restrict__ Xt,
    short* __restrict__ vt)
{
  int kt = blockIdx.x, b = blockIdx.y, dir = blockIdx.z;
  const float* X = (dir==0) ? Xt : Xi;
  __shared__ float tile[256*33];
  int tid = threadIdx.x;
#pragma unroll
  for (int i=0;i<16;i++){
    int idx = tid + i*512, row = idx>>5, col = idx&31;
    tile[row*33+col] = X[((size_t)b*C_ + row)*N_ + (size_t)kt*32 + col];
  }
  __syncthreads();
  int wid = tid>>6, l = tid&63, g = l>>4, ln = l&15;
#pragma unroll
  for (int w2=0;w2<2;w2++){
    int cc = wid*2 + w2;
    bf16x8 o;
#pragma unroll
    for (int j=0;j<8;j++){
      int c = cc*16 + ln;
      int col = 4*g + (j&3) + 16*(j>>2);
      o[j] = f2bf(tile[c*33 + col]);
    }
    *reinterpret_cast<bf16x8*>(vt + (size_t)dir*VT_SHORTS
        + (((size_t)b*128 + kt)*16 + cc)*512 + (size_t)l*8) = o;
  }
}

// ---------------- Phase 2: flash attention ----------------
// grid (32 qb, 4 b, 2 dir), block 512 (8 waves x 16 queries), kv step = 32
__global__ __launch_bounds__(512,2) void flash_kernel(
    const short* __restrict__ proj, const short* __restrict__ vt,
    float* __restrict__ outp)
{
  const int qb = blockIdx.x, b = blockIdx.y, dir = blockIdx.z;
  const short* Qt = proj + (size_t)(2*dir)*PROJ_SHORTS;
  const short* Kt = proj + (size_t)(2*dir+1)*PROJ_SHORTS;
  const short* Vt = vt + (size_t)dir*VT_SHORTS;
  float* Od = outp + (size_t)dir*((size_t)B_*N_*C_);

  __shared__ short lds[2*16384];   // [2 buf][ K: 8192 shorts | V: 8192 shorts ]

  const int tid = threadIdx.x, wid = tid>>6, l = tid&63, g = l>>4, ln = l&15;

  // hoist Q fragments (B-operand, hi/lo)
  const int tq = qb*8 + wid;
  bf16x8 qf[4][2];
#pragma unroll
  for (int kc=0;kc<4;kc++)
#pragma unroll
    for (int h=0;h<2;h++)
      qf[kc][h] = *reinterpret_cast<const bf16x8*>(
        Qt + ((((size_t)b*256 + tq)*4 + kc)*2 + h)*512 + (size_t)l*8);

  const f32x4 fzero = {0.f,0.f,0.f,0.f};
  f32x4 oacc[16];
#pragma unroll
  for (int cc=0;cc<16;cc++) oacc[cc] = fzero;
  float mrun = -INFINITY, lrun = 0.f;
  const float SCALE = 11.313708498984761f;   // sqrt(128)

  // prologue: stage step 0
  {
    const i32x4* ks = reinterpret_cast<const i32x4*>(Kt + ((size_t)(b*256))*4096) + tid*2;
    const i32x4* vs = reinterpret_cast<const i32x4*>(Vt + ((size_t)(b*128))*8192) + tid*2;
    i32x4 a0=ks[0], a1=ks[1], a2=vs[0], a3=vs[1];
    i32x4* lk = reinterpret_cast<i32x4*>(lds) + tid*2;
    i32x4* lv = reinterpret_cast<i32x4*>(lds + 8192) + tid*2;
    lk[0]=a0; lk[1]=a1; lv[0]=a2; lv[1]=a3;
  }
  __syncthreads();

#pragma unroll 1
  for (int s=0; s<128; s++){
    const int cur = s & 1;
    i32x4 st0, st1, st2, st3;
    if (s < 127){   // issue next-tile global loads early (latency hides under compute)
      const i32x4* ks = reinterpret_cast<const i32x4*>(Kt + ((size_t)(b*256 + 2*(s+1)))*4096) + tid*2;
      const i32x4* vs = reinterpret_cast<const i32x4*>(Vt + ((size_t)(b*128 + (s+1)))*8192) + tid*2;
      st0=ks[0]; st1=ks[1]; st2=vs[0]; st3=vs[1];
    }
    const short* lk = lds + cur*16384;
    const short* lv = lk + 8192;

    // S^T = K x Q^T (3-pass hi/lo), acc over Hd
    f32x4 sacc[2];
    sacc[0] = fzero; sacc[1] = fzero;
#pragma unroll
    for (int kvt=0;kvt<2;kvt++){
#pragma unroll
      for (int kc=0;kc<4;kc++){
        bf16x8 kh  = *reinterpret_cast<const bf16x8*>(lk + (size_t)(kvt*8 + kc*2 + 0)*512 + l*8);
        bf16x8 klo = *reinterpret_cast<const bf16x8*>(lk + (size_t)(kvt*8 + kc*2 + 1)*512 + l*8);
        sacc[kvt] = __builtin_amdgcn_mfma_f32_16x16x32_bf16(kh,  qf[kc][0], sacc[kvt], 0,0,0);
        sacc[kvt] = __builtin_amdgcn_mfma_f32_16x16x32_bf16(kh,  qf[kc][1], sacc[kvt], 0,0,0);
        sacc[kvt] = __builtin_amdgcn_mfma_f32_16x16x32_bf16(klo, qf[kc][0], sacc[kvt], 0,0,0);
      }
    }

    // online softmax over kv for this lane's query column (q = ln)
    float sv[8];
#pragma unroll
    for (int kvt=0;kvt<2;kvt++)
#pragma unroll
      for (int r=0;r<4;r++) sv[kvt*4+r] = sacc[kvt][r]*SCALE;
    float tmax = sv[0];
#pragma unroll
    for (int i=1;i<8;i++) tmax = fmaxf(tmax, sv[i]);
    tmax = fmaxf(tmax, __shfl_xor(tmax, 16));
    tmax = fmaxf(tmax, __shfl_xor(tmax, 32));
    float mnew  = fmaxf(mrun, tmax);
    float alpha = __expf(mrun - mnew);
    float p[8], psum = 0.f;
#pragma unroll
    for (int i=0;i<8;i++){ p[i] = __expf(sv[i]-mnew); psum += p[i]; }
    psum += __shfl_xor(psum, 16);
    psum += __shfl_xor(psum, 32);
    lrun = lrun*alpha + psum;
    mrun = mnew;

    bf16x8 pa;
#pragma unroll
    for (int i=0;i<8;i++) pa[i] = f2bf(p[i]);
#pragma unroll
    for (int cc=0;cc<16;cc++) oacc[cc] *= alpha;

    // O^T += V^T x P^T
#pragma unroll
    for (int cc=0;cc<16;cc++){
      bf16x8 vf = *reinterpret_cast<const bf16x8*>(lv + (size_t)cc*512 + l*8);
      oacc[cc] = __builtin_amdgcn_mfma_f32_16x16x32_bf16(vf, pa, oacc[cc], 0,0,0);
    }

    // write next tile into the other buffer, then one barrier
    if (s < 127){
      const int nxt = cur^1;
      i32x4* lkw = reinterpret_cast<i32x4*>(lds + nxt*16384) + tid*2;
      i32x4* lvw = reinterpret_cast<i32x4*>(lds + nxt*16384 + 8192) + tid*2;
      lkw[0]=st0; lkw[1]=st1; lvw[0]=st2; lvw[1]=st3;
    }
    __syncthreads();
  }

  // epilogue: normalize and store (O^T lanes: q = ln, c = cc*16 + 4g + r)
  float inv = 1.f / lrun;
  int qrow = qb*128 + wid*16 + ln;
  float* orow = Od + ((size_t)b*N_ + qrow)*C_;
#pragma unroll
  for (int cc=0;cc<16;cc++){
    f32x4 o = oacc[cc]*inv;
    *reinterpret_cast<f32x4*>(orow + cc*16 + 4*g) = o;
  }
}

// ---------------- host ----------------
extern "C" void kernel_launch(void* const* d_in, const int* in_sizes, int n_in,
                              void* d_out, int out_size, void* d_ws, size_t ws_size,
                              hipStream_t stream)
{
  (void)in_sizes; (void)n_in; (void)out_size; (void)ws_size;
  const float* input_i = (const float*)d_in[0];
  const float* input_t = (const float*)d_in[1];
  const float* w_img_q = (const float*)d_in[2];
  const float* bnq_g   = (const float*)d_in[3];
  const float* bnq_b   = (const float*)d_in[4];
  const float* bnq_m   = (const float*)d_in[5];
  const float* bnq_v   = (const float*)d_in[6];
  const float* w_img_k = (const float*)d_in[7];
  const float* bnk_g   = (const float*)d_in[8];
  const float* bnk_b   = (const float*)d_in[9];
  const float* bnk_m   = (const float*)d_in[10];
  const float* bnk_v   = (const float*)d_in[11];
  const float* w_text_k = (const float*)d_in[12];
  const float* b_text_k = (const float*)d_in[13];
  const float* w_text_q = (const float*)d_in[14];
  const float* b_text_q = (const float*)d_in[15];

  short* ws   = (short*)d_ws;
  short* wf   = ws;
  short* proj = ws + WF_SHORTS;
  short* vt   = ws + WF_SHORTS + 4*PROJ_SHORTS;

  // jobs: 0 = i_q (Q dir0), 1 = t_k (K dir0), 2 = t_q (Q dir1), 3 = i_k (K dir1)
  wfrag_kernel<<<dim3(4,8,8), 64, 0, stream>>>(w_img_q, w_text_k, w_text_q, w_img_k, wf);
  proj_kernel<<<dim3(16,4,4), 256, 0, stream>>>(input_i, input_t, wf,
      bnq_g, bnq_b, bnq_m, bnq_v, bnk_g, bnk_b, bnk_m, bnk_v,
      b_text_k, b_text_q, proj);
  vtile_kernel<<<dim3(128,4,2), 512, 0, stream>>>(input_i, input_t, vt);
  flash_kernel<<<dim3(32,4,2), 512, 0, stream>>>(proj, vt, (float*)d_out);
}